// Round 16
// baseline (2064.804 us; speedup 1.0000x reference)
//
#include <hip/hip_runtime.h>
#include <hip/hip_bf16.h>

#define NUM_C 1024
#define EMB   512
#define HID   512
#define BATCH 64
#define SEQ   512

typedef short bf16x8 __attribute__((ext_vector_type(8)));
typedef float f32x4  __attribute__((ext_vector_type(4)));

__device__ __forceinline__ unsigned short f2bf(float x) {
    unsigned u = __float_as_uint(x);
    u += 0x7fffu + ((u >> 16) & 1u);
    return (unsigned short)(u >> 16);
}
__device__ __forceinline__ unsigned pack2bf(float a, float b) {
    return (unsigned)f2bf(a) | ((unsigned)f2bf(b) << 16);
}
__device__ __forceinline__ float uaf(unsigned u) { return __uint_as_float(u); }

// fast tanh: exact at +-inf, ~1e-7 rel err, no branches
__device__ __forceinline__ float ftanh(float x) {
    float e = __expf(2.f * x);
    return 1.f - 2.f / (e + 1.f);
}

// ---------------------------------------------------------------------------
__global__ __launch_bounds__(256) void f32_to_bf16(const float* __restrict__ src,
                                                   unsigned short* __restrict__ dst, int n) {
    int i = blockIdx.x * 256 + threadIdx.x;
    if (i < n) dst[i] = f2bf(src[i]);
}

// ---------------------------------------------------------------------------
// fp32 vector GEMM (NT) for emb_proj = emb @ Wx^T + Wx_b + Wh_b
// ---------------------------------------------------------------------------
__global__ __launch_bounds__(256)
void gemm_nt_f32(const float* __restrict__ A, const float* __restrict__ B,
                 float* __restrict__ C, int M, int N, int K,
                 const float* __restrict__ bias1, const float* __restrict__ bias2) {
    __shared__ float As[64][33];
    __shared__ float Bs[64][33];

    const int n0 = blockIdx.x * 64;
    const int m0 = blockIdx.y * 64;
    const int tid = threadIdx.x;
    const int tx = tid & 15;
    const int ty = tid >> 4;

    float acc[4][4] = {{0.f}};

    for (int k0 = 0; k0 < K; k0 += 32) {
        #pragma unroll
        for (int i = 0; i < 2; ++i) {
            int f   = tid * 2 + i;
            int row = f >> 3;
            int kf  = f & 7;
            float4 va = *(const float4*)&A[(size_t)(m0 + row) * K + k0 + kf * 4];
            float4 vb = *(const float4*)&B[(size_t)(n0 + row) * K + k0 + kf * 4];
            As[row][kf * 4 + 0] = va.x; As[row][kf * 4 + 1] = va.y;
            As[row][kf * 4 + 2] = va.z; As[row][kf * 4 + 3] = va.w;
            Bs[row][kf * 4 + 0] = vb.x; Bs[row][kf * 4 + 1] = vb.y;
            Bs[row][kf * 4 + 2] = vb.z; Bs[row][kf * 4 + 3] = vb.w;
        }
        __syncthreads();
        #pragma unroll
        for (int kk = 0; kk < 32; ++kk) {
            float a[4], b[4];
            #pragma unroll
            for (int i = 0; i < 4; ++i) a[i] = As[ty * 4 + i][kk];
            #pragma unroll
            for (int j = 0; j < 4; ++j) b[j] = Bs[tx * 4 + j][kk];
            #pragma unroll
            for (int i = 0; i < 4; ++i)
                #pragma unroll
                for (int j = 0; j < 4; ++j)
                    acc[i][j] += a[i] * b[j];
        }
        __syncthreads();
    }

    float bb[4];
    #pragma unroll
    for (int j = 0; j < 4; ++j) {
        int n = n0 + tx * 4 + j;
        bb[j] = bias1[n] + bias2[n];
    }
    #pragma unroll
    for (int i = 0; i < 4; ++i) {
        size_t m = (size_t)(m0 + ty * 4 + i);
        float4 ov;
        ov.x = acc[i][0] + bb[0]; ov.y = acc[i][1] + bb[1];
        ov.z = acc[i][2] + bb[2]; ov.w = acc[i][3] + bb[3];
        *(float4*)&C[m * N + n0 + tx * 4] = ov;
    }
}

// ---------------------------------------------------------------------------
// LTC scan v16 = v10 skeleton (free-running, 512 blocks, 1 batch/block,
// 1 barrier/step, 2 blocks/CU TLP) + v15's resident-W mac (float4 wr_[16],
// VGPR=88 proven) + v15's fin==w==sl alignment (fin's mac chunk is its own
// slice -> fin never polls).  grid: sl = bid>>6, b = bid&63 -> partner
// blocks stride 64 -> same XCD.  __launch_bounds__(512,4) caps VGPR at 128
// (88 fits, no spill expected) -> 2 blocks/CU GUARANTEED -> all 512 blocks
// co-resident -> spin exchange cannot deadlock.
//   step s: BAR | fin(w==sl): reduce ps(s) + tanh -> h(s); atomic store to
//                 hx (remote publish), write hf (local), prefetch e(s+1)
//               | pollers (w!=sl): poll hx[s] slice-w words (f32 sentinel
//                 exp=255), drop into hf[w*64+lane]
//               | all: mac ps(s+1)[w*64+lane] = W_chunk . hf[w*64..+63]
//                 (16 uniform ds_read_b128 + 64 fma)
// ---------------------------------------------------------------------------
#define STEP16(PS_CUR, PS_NXT, S)                                              \
    __syncthreads();                                                           \
    if (fin) {                                                                 \
        float pre = e;                                                         \
        _Pragma("unroll")                                                      \
        for (int m = 0; m < 8; ++m) pre += PS_CUR[m * 64 + lane];              \
        float hn = h + (ftanh(pre) - h) * rtau;                                \
        h = hn;                                                                \
        __hip_atomic_store((unsigned*)&hxb[(S) * 512 + sl * 64 + lane],        \
                           __float_as_uint(hn), __ATOMIC_RELAXED,              \
                           __HIP_MEMORY_SCOPE_AGENT);                          \
        hf[sl * 64 + lane] = hn;                                               \
        if ((S) + 1 < SEQ)                                                     \
            e = emb_proj[(size_t)ids[(S) + 1] * HID + sl * 64 + lane];         \
    } else if ((S) + 1 < SEQ) {                                                \
        unsigned* ap = (unsigned*)&hxb[(S) * 512 + w * 64 + lane];             \
        unsigned wi = __hip_atomic_load(ap, __ATOMIC_RELAXED,                  \
                                        __HIP_MEMORY_SCOPE_AGENT);             \
        while ((wi & 0x7f800000u) == 0x7f800000u) {                            \
            __builtin_amdgcn_s_sleep(1);                                       \
            wi = __hip_atomic_load(ap, __ATOMIC_RELAXED,                       \
                                   __HIP_MEMORY_SCOPE_AGENT);                  \
        }                                                                      \
        hf[w * 64 + lane] = uaf(wi);                                           \
    }                                                                          \
    if ((S) + 1 < SEQ) {                                                       \
        float a0 = 0.f, a1 = 0.f, a2 = 0.f, a3 = 0.f;                          \
        _Pragma("unroll")                                                      \
        for (int i = 0; i < 16; ++i) {                                         \
            float4 hv = hf4[i];                                                \
            a0 = fmaf(wr_[i].x, hv.x, a0);                                     \
            a1 = fmaf(wr_[i].y, hv.y, a1);                                     \
            a2 = fmaf(wr_[i].z, hv.z, a2);                                     \
            a3 = fmaf(wr_[i].w, hv.w, a3);                                     \
        }                                                                      \
        PS_NXT[w * 64 + lane] = (a0 + a1) + (a2 + a3);                         \
    }

__global__ __launch_bounds__(512, 4)
void ltc_scan16(const int* __restrict__ q, const int* __restrict__ r,
                const float* __restrict__ emb_proj, const float* __restrict__ Wh,
                const float* __restrict__ tau, float* __restrict__ hx) {
    __shared__ float hf[512];
    __shared__ float psA[512], psB[512];
    __shared__ int   ids[512];

    const int tid  = threadIdx.x;
    const int sl   = blockIdx.x >> 6;     // slice: owns h rows sl*64..+63
    const int b    = blockIdx.x & 63;     // batch
    const int lane = tid & 63;
    const int w    = tid >> 6;            // wave = k-chunk = source slice

    // W chunk -> regs as float4[16] (resident: v15 measured VGPR=88):
    // row sl*64+lane, cols w*64..+63 (fp32, 64 VGPR)
    float4 wr_[16];
    {
        const float* wrow = Wh + (size_t)(sl * 64 + lane) * 512 + w * 64;
        #pragma unroll
        for (int i = 0; i < 16; ++i) wr_[i] = ((const float4*)wrow)[i];
    }

    ids[tid] = q[b * SEQ + tid] + NUM_C * r[b * SEQ + tid];
    psA[tid] = 0.f;                        // ps(0) = W.h(-1) = 0
    hf[tid]  = 0.f;

    const bool fin = (w == sl);            // fin's mac chunk == own slice
    float rtau = 0.f, h = 0.f, e = 0.f;
    if (fin) rtau = 1.0f / tau[sl * 64 + lane];

    float* hxb = hx + (size_t)b * SEQ * HID;
    const float4* hf4 = (const float4*)(hf + w * 64);
    __syncthreads();                       // ids, psA ready

    if (fin) e = emb_proj[(size_t)ids[0] * HID + sl * 64 + lane];

    for (int s = 0; s < SEQ; s += 2) {
        STEP16(psA, psB, s);
        STEP16(psB, psA, s + 1);
    }
}

// ---------------------------------------------------------------------------
// Output GEMM: y = sigmoid(A_f32 @ Wo_bf^T + Wo_b), bf16 MFMA 16x16x32.
// A is read in f32 (the scan's hx buffer) and converted to bf16 during LDS
// staging; B (Wo) is pre-converted bf16.
// ---------------------------------------------------------------------------
__global__ __launch_bounds__(256)
void gemm_out_bf16(const float* __restrict__ A,             // [M][512] f32
                   const unsigned short* __restrict__ B,    // [1024][512] bf16
                   const float* __restrict__ bias,
                   float* __restrict__ C, int M) {
    __shared__ __align__(16) unsigned short As[128 * 32];
    __shared__ __align__(16) unsigned short Bs[128 * 32];

    const int tid = threadIdx.x;
    const int n0 = blockIdx.x * 128;
    const int m0 = blockIdx.y * 128;
    const int w  = tid >> 6;
    const int l  = tid & 63;
    const int wr = w >> 1, wc = w & 1;
    const int lr = l & 15;
    const int lq = l >> 4;

    f32x4 acc[4][4];
    #pragma unroll
    for (int i = 0; i < 4; ++i)
        #pragma unroll
        for (int jn = 0; jn < 4; ++jn)
            acc[i][jn] = (f32x4){0.f, 0.f, 0.f, 0.f};

    for (int k0 = 0; k0 < 512; k0 += 32) {
        #pragma unroll
        for (int p = 0; p < 2; ++p) {
            int flat = p * 256 + tid;
            int row  = flat >> 2;
            int c4   = flat & 3;
            const float* asrc = &A[(size_t)(m0 + row) * 512 + k0 + c4 * 8];
            float4 v0 = ((const float4*)asrc)[0];
            float4 v1 = ((const float4*)asrc)[1];
            uint4 d;
            d.x = pack2bf(v0.x, v0.y); d.y = pack2bf(v0.z, v0.w);
            d.z = pack2bf(v1.x, v1.y); d.w = pack2bf(v1.z, v1.w);
            *(uint4*)&As[row * 32 + c4 * 8] = d;
            *(uint4*)&Bs[row * 32 + c4 * 8] =
                *(const uint4*)&B[(size_t)(n0 + row) * 512 + k0 + c4 * 8];
        }
        __syncthreads();

        bf16x8 af[4], bf[4];
        #pragma unroll
        for (int mf = 0; mf < 4; ++mf)
            af[mf] = *(const bf16x8*)&As[(wr * 64 + mf * 16 + lr) * 32 + lq * 8];
        #pragma unroll
        for (int nf = 0; nf < 4; ++nf)
            bf[nf] = *(const bf16x8*)&Bs[(wc * 64 + nf * 16 + lr) * 32 + lq * 8];

        #pragma unroll
        for (int mf = 0; mf < 4; ++mf)
            #pragma unroll
            for (int nf = 0; nf < 4; ++nf)
                acc[mf][nf] = __builtin_amdgcn_mfma_f32_16x16x32_bf16(
                    af[mf], bf[nf], acc[mf][nf], 0, 0, 0);
        __syncthreads();
    }

    #pragma unroll
    for (int mf = 0; mf < 4; ++mf) {
        #pragma unroll
        for (int nf = 0; nf < 4; ++nf) {
            int col = n0 + wc * 64 + nf * 16 + lr;
            float bb = bias[col];
            #pragma unroll
            for (int reg = 0; reg < 4; ++reg) {
                int rowm = m0 + wr * 64 + mf * 16 + lq * 4 + reg;
                float v = acc[mf][nf][reg] + bb;
                C[(size_t)rowm * 1024 + col] = 1.0f / (1.0f + expf(-v));
            }
        }
    }
}

// ---------------------------------------------------------------------------
extern "C" void kernel_launch(void* const* d_in, const int* in_sizes, int n_in,
                              void* d_out, int out_size, void* d_ws, size_t ws_size,
                              hipStream_t stream) {
    const int*   q    = (const int*)d_in[0];
    const int*   r    = (const int*)d_in[1];
    const float* emb  = (const float*)d_in[2];
    const float* Wh_w = (const float*)d_in[3];
    const float* Wh_b = (const float*)d_in[4];
    const float* Wx_w = (const float*)d_in[5];
    const float* Wx_b = (const float*)d_in[6];
    const float* tau  = (const float*)d_in[7];
    const float* Wo_w = (const float*)d_in[8];
    const float* Wo_b = (const float*)d_in[9];
    float* out = (float*)d_out;

    char* ws = (char*)d_ws;
    float*          emb_proj = (float*)ws;                           // 4 MiB
    unsigned short* Wobf     = (unsigned short*)(ws + (4u << 20));   // 1 MiB
    float*          hx       = (float*)(ws + (5u << 20));            // 64 MiB f32

    // sentinel-fill hx: 0xFF bytes -> exponent 255; any finite stored h
    // clears the sentinel test.
    hipMemsetAsync(hx, 0xFF, (size_t)BATCH * SEQ * HID * 4, stream);

    // Wo -> bf16 for the MFMA output GEMM
    f32_to_bf16<<<(1024 * 512) / 256, 256, 0, stream>>>(Wo_w, Wobf, 1024 * 512);

    // emb_proj = emb @ Wx^T + Wx_b + Wh_b (2048 distinct interaction rows)
    gemm_nt_f32<<<dim3(512 / 64, 2048 / 64), 256, 0, stream>>>(
        emb, Wx_w, emb_proj, 2048, 512, 512, Wx_b, Wh_b);

    // recurrence: 512 blocks (8 slices x 64 batches), free-running,
    // VGPR capped 128 (fits at 88) => 2 blocks/CU => co-residency guaranteed
    ltc_scan16<<<512, 512, 0, stream>>>(q, r, emb_proj, Wh_w, tau, hx);

    // y = sigmoid(hx @ Wo^T + Wo_b) via bf16 MFMA (A staged f32 -> bf16)
    gemm_out_bf16<<<dim3(1024 / 128, (BATCH * SEQ) / 128), 256, 0, stream>>>(
        hx, Wobf, Wo_b, out, BATCH * SEQ);
}

// Round 18
// 910.622 us; speedup vs baseline: 2.2675x; 2.2675x over previous
//
#include <hip/hip_runtime.h>
#include <hip/hip_bf16.h>

#define NUM_C 1024
#define EMB   512
#define HID   512
#define BATCH 64
#define SEQ   512

typedef short bf16x8 __attribute__((ext_vector_type(8)));
typedef float f32x4  __attribute__((ext_vector_type(4)));

__device__ __forceinline__ unsigned short f2bf(float x) {
    unsigned u = __float_as_uint(x);
    u += 0x7fffu + ((u >> 16) & 1u);
    return (unsigned short)(u >> 16);
}
__device__ __forceinline__ unsigned pack2bf(float a, float b) {
    return (unsigned)f2bf(a) | ((unsigned)f2bf(b) << 16);
}
__device__ __forceinline__ float uaf(unsigned u) { return __uint_as_float(u); }

// fast tanh: exact at +-inf, ~1e-7 rel err, no branches
__device__ __forceinline__ float ftanh(float x) {
    float e = __expf(2.f * x);
    return 1.f - 2.f / (e + 1.f);
}

// ---------------------------------------------------------------------------
__global__ __launch_bounds__(256) void f32_to_bf16(const float* __restrict__ src,
                                                   unsigned short* __restrict__ dst, int n) {
    int i = blockIdx.x * 256 + threadIdx.x;
    if (i < n) dst[i] = f2bf(src[i]);
}

// ---------------------------------------------------------------------------
// fp32 vector GEMM (NT) for emb_proj = emb @ Wx^T + Wx_b + Wh_b
// ---------------------------------------------------------------------------
__global__ __launch_bounds__(256)
void gemm_nt_f32(const float* __restrict__ A, const float* __restrict__ B,
                 float* __restrict__ C, int M, int N, int K,
                 const float* __restrict__ bias1, const float* __restrict__ bias2) {
    __shared__ float As[64][33];
    __shared__ float Bs[64][33];

    const int n0 = blockIdx.x * 64;
    const int m0 = blockIdx.y * 64;
    const int tid = threadIdx.x;
    const int tx = tid & 15;
    const int ty = tid >> 4;

    float acc[4][4] = {{0.f}};

    for (int k0 = 0; k0 < K; k0 += 32) {
        #pragma unroll
        for (int i = 0; i < 2; ++i) {
            int f   = tid * 2 + i;
            int row = f >> 3;
            int kf  = f & 7;
            float4 va = *(const float4*)&A[(size_t)(m0 + row) * K + k0 + kf * 4];
            float4 vb = *(const float4*)&B[(size_t)(n0 + row) * K + k0 + kf * 4];
            As[row][kf * 4 + 0] = va.x; As[row][kf * 4 + 1] = va.y;
            As[row][kf * 4 + 2] = va.z; As[row][kf * 4 + 3] = va.w;
            Bs[row][kf * 4 + 0] = vb.x; Bs[row][kf * 4 + 1] = vb.y;
            Bs[row][kf * 4 + 2] = vb.z; Bs[row][kf * 4 + 3] = vb.w;
        }
        __syncthreads();
        #pragma unroll
        for (int kk = 0; kk < 32; ++kk) {
            float a[4], b[4];
            #pragma unroll
            for (int i = 0; i < 4; ++i) a[i] = As[ty * 4 + i][kk];
            #pragma unroll
            for (int j = 0; j < 4; ++j) b[j] = Bs[tx * 4 + j][kk];
            #pragma unroll
            for (int i = 0; i < 4; ++i)
                #pragma unroll
                for (int j = 0; j < 4; ++j)
                    acc[i][j] += a[i] * b[j];
        }
        __syncthreads();
    }

    float bb[4];
    #pragma unroll
    for (int j = 0; j < 4; ++j) {
        int n = n0 + tx * 4 + j;
        bb[j] = bias1[n] + bias2[n];
    }
    #pragma unroll
    for (int i = 0; i < 4; ++i) {
        size_t m = (size_t)(m0 + ty * 4 + i);
        float4 ov;
        ov.x = acc[i][0] + bb[0]; ov.y = acc[i][1] + bb[1];
        ov.z = acc[i][2] + bb[2]; ov.w = acc[i][3] + bb[3];
        *(float4*)&C[m * N + n0 + tx * 4] = ov;
    }
}

// ---------------------------------------------------------------------------
// LTC scan v18: deadlock-proof geometry + LDS-free readlane mac + early polls.
//  - grid 256 = 8 slices x 32 batch-pairs, 512 thr, 1 block/CU UNCONDITIONAL
//    (256 blocks always co-resident regardless of VGPR -> spin can't deadlock)
//  - W f32 resident in float4 wr_[16] (r13 proved residency for this combo)
//  - mac: 64 v_readlane + 64 fma from the polled h word `wi` in each lane's
//    VGPR -- zero LDS on the h path (v15 was LDS-pipe-bound: 16 ds_read_b128
//    x 8 waves ~ 1536cy/phase); fin wave (w==sl) readlanes its OWN h.
//  - polls: ISSUE load at phase top, mac the other rail (~500cy independent
//    work), THEN spin-check -- L2 visibility hides under the mac.
// Iteration s (2 phases, 1 barrier each):
//  P1: pollers issue ldB=hxB[s-1]; fin finishB(s-1) (psB reduce, tanh,
//      publish hxB[s-1], wiB=own h, prefetch eB(s)); ALL macA(s) from wiA
//      -> psA; pollers spin ldB -> wiB.                             BAR
//  P2: pollers issue ldA=hxA[s]; fin finishA(s) (psA, publish hxA[s],
//      wiA=own h, prefetch eA(s+1)); ALL macB(s) from wiB -> psB;
//      pollers spin ldA -> wiA.                                     BAR
// Epilogue: finishB(SEQ-1).  Exchange: f32 words, sentinel = exp 255
// (memset 0xFF; |h|<1 => exp<=126).  Partner blocks stride 32 -> same XCD.
// ---------------------------------------------------------------------------
__global__ __launch_bounds__(512, 2)
void ltc_scan18(const int* __restrict__ q, const int* __restrict__ r,
                const float* __restrict__ emb_proj, const float* __restrict__ Wh,
                const float* __restrict__ tau, float* __restrict__ hx) {
    __shared__ float psA[512], psB[512];
    __shared__ int   idA[512], idB[512];

    const int tid  = threadIdx.x;
    const int sl   = blockIdx.x >> 5;     // slice: owns h rows sl*64..+63
    const int bp   = blockIdx.x & 31;     // batch pair
    const int bA   = bp * 2, bB = bA + 1;
    const int lane = tid & 63;
    const int w    = tid >> 6;            // wave = k-chunk = source slice

    // W chunk -> regs as float4[16]: row sl*64+lane, cols w*64..+63
    float4 wr_[16];
    {
        const float* wrow = Wh + (size_t)(sl * 64 + lane) * 512 + w * 64;
        #pragma unroll
        for (int i = 0; i < 16; ++i) wr_[i] = ((const float4*)wrow)[i];
    }

    idA[tid] = q[bA * SEQ + tid] + NUM_C * r[bA * SEQ + tid];
    idB[tid] = q[bB * SEQ + tid] + NUM_C * r[bB * SEQ + tid];
    psA[tid] = 0.f;                        // ps_A(0) = W.h_A(-1) = 0

    const bool fin = (w == sl);            // fin's mac chunk == own slice
    float rtau = 0.f, hA = 0.f, hB = 0.f, eA = 0.f, eB = 0.f;
    int wiA = 0, wiB = 0;                  // h words (f32 bits); h(-1)=0
    if (fin) rtau = 1.0f / tau[sl * 64 + lane];

    unsigned* hxAw = (unsigned*)(hx + (size_t)bA * SEQ * HID);
    unsigned* hxBw = (unsigned*)(hx + (size_t)bB * SEQ * HID);
    __syncthreads();                       // ids, psA ready

    if (fin) {
        eA = emb_proj[(size_t)idA[0] * HID + sl * 64 + lane];
        eB = emb_proj[(size_t)idB[0] * HID + sl * 64 + lane];
    }

    for (int s = 0; s < SEQ; ++s) {
        // ---------------- P1 ----------------
        unsigned ldB = 0;
        if (!fin && s > 0)                                   // issue EARLY
            ldB = __hip_atomic_load(&hxBw[(s - 1) * 512 + w * 64 + lane],
                                    __ATOMIC_RELAXED, __HIP_MEMORY_SCOPE_AGENT);
        if (fin && s > 0) {                                  // finish B(s-1)
            float pre = eB;
            #pragma unroll
            for (int m = 0; m < 8; ++m) pre += psB[m * 64 + lane];
            float hn = hB + (ftanh(pre) - hB) * rtau;
            hB = hn;
            __hip_atomic_store(&hxBw[(s - 1) * 512 + sl * 64 + lane],
                               __float_as_uint(hn), __ATOMIC_RELAXED,
                               __HIP_MEMORY_SCOPE_AGENT);
            wiB = (int)__float_as_uint(hn);
            eB = emb_proj[(size_t)idB[s] * HID + sl * 64 + lane];
        }
        {   // mac A(s) from wiA (register readlane broadcast, no LDS)
            float a0 = 0.f, a1 = 0.f, a2 = 0.f, a3 = 0.f;
            #pragma unroll
            for (int i = 0; i < 16; ++i) {
                a0 = fmaf(wr_[i].x,
                     uaf((unsigned)__builtin_amdgcn_readlane(wiA, 4 * i + 0)), a0);
                a1 = fmaf(wr_[i].y,
                     uaf((unsigned)__builtin_amdgcn_readlane(wiA, 4 * i + 1)), a1);
                a2 = fmaf(wr_[i].z,
                     uaf((unsigned)__builtin_amdgcn_readlane(wiA, 4 * i + 2)), a2);
                a3 = fmaf(wr_[i].w,
                     uaf((unsigned)__builtin_amdgcn_readlane(wiA, 4 * i + 3)), a3);
            }
            psA[w * 64 + lane] = (a0 + a1) + (a2 + a3);
        }
        if (!fin && s > 0) {                                 // spin LATE
            while ((ldB & 0x7f800000u) == 0x7f800000u) {
                __builtin_amdgcn_s_sleep(1);
                ldB = __hip_atomic_load(&hxBw[(s - 1) * 512 + w * 64 + lane],
                                        __ATOMIC_RELAXED, __HIP_MEMORY_SCOPE_AGENT);
            }
            wiB = (int)ldB;
        }
        __syncthreads();

        // ---------------- P2 ----------------
        unsigned ldA = 0;
        if (!fin)                                            // issue EARLY
            ldA = __hip_atomic_load(&hxAw[s * 512 + w * 64 + lane],
                                    __ATOMIC_RELAXED, __HIP_MEMORY_SCOPE_AGENT);
        if (fin) {                                           // finish A(s)
            float pre = eA;
            #pragma unroll
            for (int m = 0; m < 8; ++m) pre += psA[m * 64 + lane];
            float hn = hA + (ftanh(pre) - hA) * rtau;
            hA = hn;
            __hip_atomic_store(&hxAw[s * 512 + sl * 64 + lane],
                               __float_as_uint(hn), __ATOMIC_RELAXED,
                               __HIP_MEMORY_SCOPE_AGENT);
            wiA = (int)__float_as_uint(hn);
            if (s + 1 < SEQ)
                eA = emb_proj[(size_t)idA[s + 1] * HID + sl * 64 + lane];
        }
        {   // mac B(s) from wiB
            float a0 = 0.f, a1 = 0.f, a2 = 0.f, a3 = 0.f;
            #pragma unroll
            for (int i = 0; i < 16; ++i) {
                a0 = fmaf(wr_[i].x,
                     uaf((unsigned)__builtin_amdgcn_readlane(wiB, 4 * i + 0)), a0);
                a1 = fmaf(wr_[i].y,
                     uaf((unsigned)__builtin_amdgcn_readlane(wiB, 4 * i + 1)), a1);
                a2 = fmaf(wr_[i].z,
                     uaf((unsigned)__builtin_amdgcn_readlane(wiB, 4 * i + 2)), a2);
                a3 = fmaf(wr_[i].w,
                     uaf((unsigned)__builtin_amdgcn_readlane(wiB, 4 * i + 3)), a3);
            }
            psB[w * 64 + lane] = (a0 + a1) + (a2 + a3);
        }
        if (!fin) {                                          // spin LATE
            while ((ldA & 0x7f800000u) == 0x7f800000u) {
                __builtin_amdgcn_s_sleep(1);
                ldA = __hip_atomic_load(&hxAw[s * 512 + w * 64 + lane],
                                        __ATOMIC_RELAXED, __HIP_MEMORY_SCOPE_AGENT);
            }
            wiA = (int)ldA;
        }
        __syncthreads();
    }

    // epilogue: finish B(SEQ-1) (hx must be complete for the output GEMM)
    if (fin) {
        float pre = eB;
        #pragma unroll
        for (int m = 0; m < 8; ++m) pre += psB[m * 64 + lane];
        float hn = hB + (ftanh(pre) - hB) * rtau;
        __hip_atomic_store(&hxBw[(SEQ - 1) * 512 + sl * 64 + lane],
                           __float_as_uint(hn), __ATOMIC_RELAXED,
                           __HIP_MEMORY_SCOPE_AGENT);
    }
}

// ---------------------------------------------------------------------------
// Output GEMM: y = sigmoid(A_f32 @ Wo_bf^T + Wo_b), bf16 MFMA 16x16x32.
// A is read in f32 (the scan's hx buffer) and converted to bf16 during LDS
// staging; B (Wo) is pre-converted bf16.
// ---------------------------------------------------------------------------
__global__ __launch_bounds__(256)
void gemm_out_bf16(const float* __restrict__ A,             // [M][512] f32
                   const unsigned short* __restrict__ B,    // [1024][512] bf16
                   const float* __restrict__ bias,
                   float* __restrict__ C, int M) {
    __shared__ __align__(16) unsigned short As[128 * 32];
    __shared__ __align__(16) unsigned short Bs[128 * 32];

    const int tid = threadIdx.x;
    const int n0 = blockIdx.x * 128;
    const int m0 = blockIdx.y * 128;
    const int w  = tid >> 6;
    const int l  = tid & 63;
    const int wr = w >> 1, wc = w & 1;
    const int lr = l & 15;
    const int lq = l >> 4;

    f32x4 acc[4][4];
    #pragma unroll
    for (int i = 0; i < 4; ++i)
        #pragma unroll
        for (int jn = 0; jn < 4; ++jn)
            acc[i][jn] = (f32x4){0.f, 0.f, 0.f, 0.f};

    for (int k0 = 0; k0 < 512; k0 += 32) {
        #pragma unroll
        for (int p = 0; p < 2; ++p) {
            int flat = p * 256 + tid;
            int row  = flat >> 2;
            int c4   = flat & 3;
            const float* asrc = &A[(size_t)(m0 + row) * 512 + k0 + c4 * 8];
            float4 v0 = ((const float4*)asrc)[0];
            float4 v1 = ((const float4*)asrc)[1];
            uint4 d;
            d.x = pack2bf(v0.x, v0.y); d.y = pack2bf(v0.z, v0.w);
            d.z = pack2bf(v1.x, v1.y); d.w = pack2bf(v1.z, v1.w);
            *(uint4*)&As[row * 32 + c4 * 8] = d;
            *(uint4*)&Bs[row * 32 + c4 * 8] =
                *(const uint4*)&B[(size_t)(n0 + row) * 512 + k0 + c4 * 8];
        }
        __syncthreads();

        bf16x8 af[4], bf[4];
        #pragma unroll
        for (int mf = 0; mf < 4; ++mf)
            af[mf] = *(const bf16x8*)&As[(wr * 64 + mf * 16 + lr) * 32 + lq * 8];
        #pragma unroll
        for (int nf = 0; nf < 4; ++nf)
            bf[nf] = *(const bf16x8*)&Bs[(wc * 64 + nf * 16 + lr) * 32 + lq * 8];

        #pragma unroll
        for (int mf = 0; mf < 4; ++mf)
            #pragma unroll
            for (int nf = 0; nf < 4; ++nf)
                acc[mf][nf] = __builtin_amdgcn_mfma_f32_16x16x32_bf16(
                    af[mf], bf[nf], acc[mf][nf], 0, 0, 0);
        __syncthreads();
    }

    #pragma unroll
    for (int mf = 0; mf < 4; ++mf) {
        #pragma unroll
        for (int nf = 0; nf < 4; ++nf) {
            int col = n0 + wc * 64 + nf * 16 + lr;
            float bb = bias[col];
            #pragma unroll
            for (int reg = 0; reg < 4; ++reg) {
                int rowm = m0 + wr * 64 + mf * 16 + lq * 4 + reg;
                float v = acc[mf][nf][reg] + bb;
                C[(size_t)rowm * 1024 + col] = 1.0f / (1.0f + expf(-v));
            }
        }
    }
}

// ---------------------------------------------------------------------------
extern "C" void kernel_launch(void* const* d_in, const int* in_sizes, int n_in,
                              void* d_out, int out_size, void* d_ws, size_t ws_size,
                              hipStream_t stream) {
    const int*   q    = (const int*)d_in[0];
    const int*   r    = (const int*)d_in[1];
    const float* emb  = (const float*)d_in[2];
    const float* Wh_w = (const float*)d_in[3];
    const float* Wh_b = (const float*)d_in[4];
    const float* Wx_w = (const float*)d_in[5];
    const float* Wx_b = (const float*)d_in[6];
    const float* tau  = (const float*)d_in[7];
    const float* Wo_w = (const float*)d_in[8];
    const float* Wo_b = (const float*)d_in[9];
    float* out = (float*)d_out;

    char* ws = (char*)d_ws;
    float*          emb_proj = (float*)ws;                           // 4 MiB
    unsigned short* Wobf     = (unsigned short*)(ws + (4u << 20));   // 1 MiB
    float*          hx       = (float*)(ws + (5u << 20));            // 64 MiB f32

    // sentinel-fill hx: 0xFF bytes -> exponent 255; any finite stored h
    // clears the sentinel test.
    hipMemsetAsync(hx, 0xFF, (size_t)BATCH * SEQ * HID * 4, stream);

    // Wo -> bf16 for the MFMA output GEMM
    f32_to_bf16<<<(1024 * 512) / 256, 256, 0, stream>>>(Wo_w, Wobf, 1024 * 512);

    // emb_proj = emb @ Wx^T + Wx_b + Wh_b (2048 distinct interaction rows)
    gemm_nt_f32<<<dim3(512 / 64, 2048 / 64), 256, 0, stream>>>(
        emb, Wx_w, emb_proj, 2048, 512, 512, Wx_b, Wh_b);

    // recurrence: 256 blocks (8 slices x 32 batch-pairs), 1 block/CU
    // unconditional => co-residency (and thus progress) guaranteed.
    ltc_scan18<<<256, 512, 0, stream>>>(q, r, emb_proj, Wh_w, tau, hx);

    // y = sigmoid(hx @ Wo^T + Wo_b) via bf16 MFMA (A staged f32 -> bf16)
    gemm_out_bf16<<<dim3(1024 / 128, (BATCH * SEQ) / 128), 256, 0, stream>>>(
        hx, Wobf, Wo_b, out, BATCH * SEQ);
}